// Round 9
// baseline (138.541 us; speedup 1.0000x reference)
//
#include <hip/hip_runtime.h>

// LinearCRF forward (unlabeled logZ + labeled score), MI355X.
//
// Masked transitions (T[:,START]=T[END,:]=T[:,PAD]=T[PAD,:]=-1e4) close the
// exp-domain recursion over states {0,1}: P_t = N_t * P_{t-1},
//   N_t[j][i] = exp(T[i][j]) * exp(x_t[j]),  i,j in {0,1}.
// v4: 2 waves/row x 4 steps/lane, COMPACTED LDS staging (only x[t][0..1]
// kept -> 12.2KB/block -> 8 blocks/CU, full 32-wave occupancy), shfl_xor
// butterfly + cross-wave LDS combine, single kernel: per-block partials in
// d_ws + last-block-done final reduce (no atomic-contended accumulate).

#define ROWS 2   // rows per block
#define WPR 2    // waves per row
#define SGS 4    // time-steps per lane (S=512: 512/(64*WPR) = 4)

__device__ __forceinline__ void rescale4(float& a, float& b, float& c, float& d,
                                         float& logZ) {
    float m = fmaxf(fmaxf(a, b), fmaxf(c, d));
    int k = (__float_as_int(m) >> 23) & 0xFF;          // biased exponent
    float scale = __int_as_float((254 - k) << 23);      // 2^(127-k), exact
    logZ += (float)(k - 127) * 0.69314718055994530942f;
    a *= scale; b *= scale; c *= scale; d *= scale;
}

template <int S>
__global__ __launch_bounds__(64 * ROWS * WPR) void crf_fwd_k1(
    const float* __restrict__ lstm,   // [B,S,5]
    const float* __restrict__ trans,  // [5,5]
    const int* __restrict__ lens,     // [B]
    const int* __restrict__ tags,     // [B,S]
    float* __restrict__ ws,           // [nblk*2] partials, then uint counter
    float* __restrict__ out,          // [2] written by last block only
    int B) {
    constexpr int F4R = S * 5 / 4;   // float4s per lstm row (640 at S=512)
    constexpr int T4R = S / 4;       // int4s per tag row (128 at S=512)
    constexpr int NTHR = 64 * ROWS * WPR;  // 256

    __shared__ float xsc[ROWS][S * 2];   // compacted x[t][0..1]: 8 KB
    __shared__ int4 tg4[ROWS][T4R];      // 4 KB
    __shared__ float cw[ROWS][WPR][6];   // m00,m01,m10,m11,logZ,lab
    __shared__ float red[2][ROWS];
    __shared__ int islast;

    const int tid = threadIdx.x;
    const int lane = tid & 63;
    const int w = tid >> 6;          // wave id in block [0,4)
    const int row = w / WPR;         // which row this wave works on
    const int half = w % WPR;        // time-half of the row
    const int b0 = blockIdx.x * ROWS;

    const int lenA = (b0 < B) ? lens[b0] : 0;
    const int lenB = (b0 + 1 < B) ? lens[b0 + 1] : 0;

    // ---- block-wide coalesced staging, len-bounded, compacted to cols 0,1 ----
    {
        const int nf4_0 = (lenA * 5 + 3) >> 2;
        const int nf4_1 = (lenB * 5 + 3) >> 2;
#pragma unroll
        for (int i = 0; i < (ROWS * F4R) / NTHR; ++i) {  // 5 iters at S=512
            int idx = tid + NTHR * i;
            int r = idx / F4R;
            int j = idx - r * F4R;
            int nf4 = r ? nf4_1 : nf4_0;
            if (j < nf4) {
                const float4* src =
                    reinterpret_cast<const float4*>(lstm + (size_t)(b0 + r) * S * 5);
                float4 v = src[j];
                unsigned p0 = 4u * (unsigned)j;
                float e[4] = {v.x, v.y, v.z, v.w};
#pragma unroll
                for (int q = 0; q < 4; ++q) {
                    unsigned p = p0 + q;
                    unsigned t = p / 5u;
                    unsigned c = p - 5u * t;
                    if (c < 2u) xsc[r][t * 2 + c] = e[q];
                }
            }
        }
        const int nt4_0 = (lenA + 3) >> 2;
        const int nt4_1 = (lenB + 3) >> 2;
        {
            int idx = tid;  // 256 threads cover ROWS*T4R = 256 at S=512
            if (idx < ROWS * T4R) {
                int r = idx / T4R;
                int j = idx - r * T4R;
                int nt4 = r ? nt4_1 : nt4_0;
                if (j < nt4) {
                    const int4* tsrc =
                        reinterpret_cast<const int4*>(tags + (size_t)(b0 + r) * S);
                    tg4[r][j] = tsrc[j];
                }
            }
        }
    }
    __syncthreads();

    const int b = b0 + row;
    const bool valid = (b < B);
    const int len = row ? lenB : lenA;
    const float2* __restrict__ xr2 = reinterpret_cast<const float2*>(xsc[row]);
    const int* __restrict__ tr = reinterpret_cast<const int*>(tg4[row]);

    // transition scalars (uniform, L2-resident)
    const float T00 = trans[0], T01 = trans[1];
    const float T04 = trans[4];
    const float T10 = trans[5], T11 = trans[6];
    const float T14 = trans[9];
    const float T30 = trans[15], T31 = trans[16];
    const float E00 = __expf(T00), E01 = __expf(T01);
    const float E10 = __expf(T10), E11 = __expf(T11);

    // this lane's segment: t in [tA, tB) subset of [1, len)
    const int tA = 1 + (half * 64 + lane) * SGS;
    const int tB = min(tA + SGS, len);

    float m00 = 1.f, m01 = 0.f, m10 = 0.f, m11 = 1.f;
    float logZ = 0.f;
    float lab = 0.f;

    if (tA < len) {
        int prev = tr[tA - 1] & 1;
#pragma unroll
        for (int u = 0; u < SGS; ++u) {
            int t = tA + u;
            if (t < tB) {
                float2 xv = xr2[t];
                float x0 = xv.x, x1 = xv.y;
                int tg = tr[t] & 1;
                float ex0 = __expf(x0), ex1 = __expf(x1);
                // N = [[E00*ex0, E10*ex0], [E01*ex1, E11*ex1]]
                float n00 = E00 * ex0, n01 = E10 * ex0;
                float n10 = E01 * ex1, n11 = E11 * ex1;
                // M <- N * M
                float r00 = fmaf(n00, m00, n01 * m10);
                float r01 = fmaf(n00, m01, n01 * m11);
                float r10 = fmaf(n10, m00, n11 * m10);
                float r11 = fmaf(n10, m01, n11 * m11);
                m00 = r00; m01 = r01; m10 = r10; m11 = r11;
                // labeled chain: T[prev][tg] + x[t][tg]
                int idx = (prev << 1) | tg;
                float Tpt = (idx == 0) ? T00 : (idx == 1) ? T01
                                         : (idx == 2) ? T10 : T11;
                lab += Tpt + (tg ? x1 : x0);
                if (t == len - 1) lab += tg ? T14 : T04;  // + T[tags[len-1]][END]
                prev = tg;
            }
        }
        rescale4(m00, m01, m10, m11, logZ);  // <= 4 steps: one rescale suffices
    }

    // butterfly within wave: ordered product (higher lane = later = LEFT)
#pragma unroll
    for (int msk = 1; msk < 64; msk <<= 1) {
        float o00 = __shfl_xor(m00, msk);
        float o01 = __shfl_xor(m01, msk);
        float o10 = __shfl_xor(m10, msk);
        float o11 = __shfl_xor(m11, msk);
        float oz = __shfl_xor(logZ, msk);
        float ol = __shfl_xor(lab, msk);
        const bool upper = (lane & msk) != 0;
        float a00 = upper ? m00 : o00, a01 = upper ? m01 : o01;
        float a10 = upper ? m10 : o10, a11 = upper ? m11 : o11;
        float c00 = upper ? o00 : m00, c01 = upper ? o01 : m01;
        float c10 = upper ? o10 : m10, c11 = upper ? o11 : m11;
        m00 = fmaf(a00, c00, a01 * c10);
        m01 = fmaf(a00, c01, a01 * c11);
        m10 = fmaf(a10, c00, a11 * c10);
        m11 = fmaf(a10, c01, a11 * c11);
        logZ += oz;
        lab += ol;
        rescale4(m00, m01, m10, m11, logZ);
    }

    // cross-wave combine per row via LDS
    if (lane == 0) {
        cw[row][half][0] = m00; cw[row][half][1] = m01;
        cw[row][half][2] = m10; cw[row][half][3] = m11;
        cw[row][half][4] = logZ; cw[row][half][5] = lab;
    }
    __syncthreads();

    if (half == 0 && lane == 0) {
        float unlab_w = 0.f, lab_w = 0.f;
        if (valid) {
            // A = earlier half, B = later half; total = MB * MA
            float a00 = cw[row][0][0], a01 = cw[row][0][1];
            float a10 = cw[row][0][2], a11 = cw[row][0][3];
            float b00 = cw[row][1][0], b01 = cw[row][1][1];
            float b10 = cw[row][1][2], b11 = cw[row][1][3];
            float M00 = fmaf(b00, a00, b01 * a10);
            float M01 = fmaf(b00, a01, b01 * a11);
            float M10 = fmaf(b10, a00, b11 * a10);
            float M11 = fmaf(b10, a01, b11 * a11);
            float lz = cw[row][0][4] + cw[row][1][4];
            float lb = cw[row][0][5] + cw[row][1][5];

            float x00 = xsc[row][0], x01 = xsc[row][1];
            int tg0 = tr[0] & 1;
            float p0 = __expf(T30 + x00);   // P0 = exp(T[START][j] + x0[j])
            float p1 = __expf(T31 + x01);
            float f0 = fmaf(M00, p0, M01 * p1);
            float f1 = fmaf(M10, p0, M11 * p1);
            float s = fmaf(f0, __expf(T04), f1 * __expf(T14));
            unlab_w = lz + __logf(s);
            lab_w = lb + (tg0 ? T31 + x01 : T30 + x00);  // begin term
            if (len == 1) lab_w += tg0 ? T14 : T04;      // end term if loop never ran
        }
        red[0][row] = unlab_w;
        red[1][row] = lab_w;
    }
    __syncthreads();

    const int nblk = gridDim.x;
    unsigned int* cnt = reinterpret_cast<unsigned int*>(ws + (size_t)nblk * 2);
    if (tid == 0) {
        float su = 0.f, sl = 0.f;
#pragma unroll
        for (int r = 0; r < ROWS; ++r) {
            su += red[0][r];
            sl += red[1][r];
        }
        ws[blockIdx.x * 2 + 0] = su;
        ws[blockIdx.x * 2 + 1] = sl;
        __threadfence();                                   // partials visible
        unsigned t = atomicAdd(cnt, 1u);                   // device-scope
        islast = (t == (unsigned)nblk - 1u) ? 1 : 0;
    }
    __syncthreads();

    if (islast) {
        __threadfence();  // acquire all partials
        float su = 0.f, sl = 0.f;
        const float2* p = reinterpret_cast<const float2*>(ws);
        for (int i = tid; i < nblk; i += NTHR) {
            float2 v = p[i];
            su += v.x;
            sl += v.y;
        }
#pragma unroll
        for (int m = 1; m < 64; m <<= 1) {
            su += __shfl_xor(su, m);
            sl += __shfl_xor(sl, m);
        }
        __shared__ float fr[2][ROWS * WPR];
        if (lane == 0) {
            fr[0][w] = su;
            fr[1][w] = sl;
        }
        __syncthreads();
        if (tid == 0) {
            float a = 0.f, bsum = 0.f;
#pragma unroll
            for (int i = 0; i < ROWS * WPR; ++i) {
                a += fr[0][i];
                bsum += fr[1][i];
            }
            out[0] = a;
            out[1] = bsum;
        }
    }
}

// ---- generic fallback (any S): unstaged wave-parallel, atomics ----
__global__ __launch_bounds__(256) void crf_fwd_wave_gen(
    const float* __restrict__ lstm, const float* __restrict__ trans,
    const int* __restrict__ lens, const int* __restrict__ tags,
    float* __restrict__ out, int B, int S, int Sg) {
    const int lane = threadIdx.x & 63;
    const int wid = threadIdx.x >> 6;
    const int nw = blockDim.x >> 6;
    const int b = blockIdx.x * nw + wid;
    const bool valid = (b < B);

    const float T00 = trans[0], T01 = trans[1];
    const float T04 = trans[4];
    const float T10 = trans[5], T11 = trans[6];
    const float T14 = trans[9];
    const float T30 = trans[15], T31 = trans[16];
    const float E00 = __expf(T00), E01 = __expf(T01);
    const float E10 = __expf(T10), E11 = __expf(T11);

    const int len = valid ? lens[b] : 0;
    const float* __restrict__ xrow = lstm + (size_t)b * S * 5;
    const int* __restrict__ trow = tags + (size_t)b * S;

    const int tA = 1 + lane * Sg;
    const int tB = min(tA + Sg, len);

    float m00 = 1.f, m01 = 0.f, m10 = 0.f, m11 = 1.f;
    float logZ = 0.f, lab = 0.f;

    if (tA < len) {
        int prev = trow[tA - 1] & 1;
        for (int u = 0; u < Sg; ++u) {
            int t = tA + u;
            if (t < tB) {
                float x0 = xrow[t * 5 + 0];
                float x1 = xrow[t * 5 + 1];
                int tg = trow[t] & 1;
                float ex0 = __expf(x0), ex1 = __expf(x1);
                float n00 = E00 * ex0, n01 = E10 * ex0;
                float n10 = E01 * ex1, n11 = E11 * ex1;
                float r00 = fmaf(n00, m00, n01 * m10);
                float r01 = fmaf(n00, m01, n01 * m11);
                float r10 = fmaf(n10, m00, n11 * m10);
                float r11 = fmaf(n10, m01, n11 * m11);
                m00 = r00; m01 = r01; m10 = r10; m11 = r11;
                int idx = (prev << 1) | tg;
                float Tpt = (idx == 0) ? T00 : (idx == 1) ? T01
                                         : (idx == 2) ? T10 : T11;
                lab += Tpt + (tg ? x1 : x0);
                if (t == len - 1) lab += tg ? T14 : T04;
                prev = tg;
            }
            if ((u & 3) == 3) rescale4(m00, m01, m10, m11, logZ);
        }
        rescale4(m00, m01, m10, m11, logZ);
    }

#pragma unroll
    for (int msk = 1; msk < 64; msk <<= 1) {
        float o00 = __shfl_xor(m00, msk);
        float o01 = __shfl_xor(m01, msk);
        float o10 = __shfl_xor(m10, msk);
        float o11 = __shfl_xor(m11, msk);
        float oz = __shfl_xor(logZ, msk);
        float ol = __shfl_xor(lab, msk);
        const bool upper = (lane & msk) != 0;
        float a00 = upper ? m00 : o00, a01 = upper ? m01 : o01;
        float a10 = upper ? m10 : o10, a11 = upper ? m11 : o11;
        float c00 = upper ? o00 : m00, c01 = upper ? o01 : m01;
        float c10 = upper ? o10 : m10, c11 = upper ? o11 : m11;
        m00 = fmaf(a00, c00, a01 * c10);
        m01 = fmaf(a00, c01, a01 * c11);
        m10 = fmaf(a10, c00, a11 * c10);
        m11 = fmaf(a10, c01, a11 * c11);
        logZ += oz;
        lab += ol;
        rescale4(m00, m01, m10, m11, logZ);
    }

    __shared__ float red[2][8];
    float unlab_w = 0.f, lab_w = 0.f;
    if (lane == 0 && valid) {
        float x00 = xrow[0], x01 = xrow[1];
        int tg0 = trow[0] & 1;
        float p0 = __expf(T30 + x00);
        float p1 = __expf(T31 + x01);
        float f0 = fmaf(m00, p0, m01 * p1);
        float f1 = fmaf(m10, p0, m11 * p1);
        float s = fmaf(f0, __expf(T04), f1 * __expf(T14));
        unlab_w = logZ + __logf(s);
        lab_w = lab + (tg0 ? T31 + x01 : T30 + x00);
        if (len == 1) lab_w += tg0 ? T14 : T04;
    }
    if (lane == 0) {
        red[0][wid] = unlab_w;
        red[1][wid] = lab_w;
    }
    __syncthreads();
    if (threadIdx.x == 0) {
        float su = 0.f, sl = 0.f;
        for (int w = 0; w < nw; ++w) {
            su += red[0][w];
            sl += red[1][w];
        }
        atomicAdd(&out[0], su);
        atomicAdd(&out[1], sl);
    }
}

extern "C" void kernel_launch(void* const* d_in, const int* in_sizes, int n_in,
                              void* d_out, int out_size, void* d_ws, size_t ws_size,
                              hipStream_t stream) {
    const float* lstm = (const float*)d_in[0];
    const float* trans = (const float*)d_in[1];
    const int* lens = (const int*)d_in[2];
    const int* tags = (const int*)d_in[3];
    float* out = (float*)d_out;
    float* ws = (float*)d_ws;

    const int B = in_sizes[2];
    const int S = in_sizes[3] / B;

    if (S == 512) {
        const int nblk = (B + ROWS - 1) / ROWS;  // 2048 at B=4096
        // zero the last-block ticket counter (lives after nblk*2 partials)
        hipMemsetAsync((char*)d_ws + (size_t)nblk * 2 * sizeof(float), 0,
                       sizeof(unsigned int), stream);
        dim3 block(64 * ROWS * WPR);             // 256 threads
        crf_fwd_k1<512><<<nblk, block, 0, stream>>>(lstm, trans, lens, tags,
                                                    ws, out, B);
    } else {
        const int Sg = (S - 1 + 63) >> 6;
        hipMemsetAsync(out, 0, out_size * sizeof(float), stream);
        dim3 block(256);
        dim3 grid((B + 3) / 4);
        crf_fwd_wave_gen<<<grid, block, 0, stream>>>(lstm, trans, lens, tags,
                                                     out, B, S, Sg);
    }
}

// Round 10
// 98.703 us; speedup vs baseline: 1.4036x; 1.4036x over previous
//
#include <hip/hip_runtime.h>

// LinearCRF forward (unlabeled logZ + labeled score), MI355X.
//
// Masked transitions (T[:,START]=T[END,:]=T[:,PAD]=T[PAD,:]=-1e4) close the
// exp-domain recursion over states {0,1}: P_t = N_t * P_{t-1},
//   N_t[j][i] = exp(T[i][j]) * exp(x_t[j]),  i,j in {0,1}.
// v5 == v3 (round-7 best, 99.66us): 2 waves/row x 4 steps/lane, block-
// coalesced b128 LDS staging (len-bounded), shfl_xor butterfly + cross-wave
// LDS combine, per-block partials to d_ws + separate deterministic reduce
// kernel (kernel boundary provides ordering -- NO per-block threadfence).

#define ROWS 2   // rows per block
#define WPR 2    // waves per row
#define SGS 4    // time-steps per lane (S=512: 512/(64*WPR) = 4)

__device__ __forceinline__ void rescale4(float& a, float& b, float& c, float& d,
                                         float& logZ) {
    float m = fmaxf(fmaxf(a, b), fmaxf(c, d));
    int k = (__float_as_int(m) >> 23) & 0xFF;          // biased exponent
    float scale = __int_as_float((254 - k) << 23);      // 2^(127-k), exact
    logZ += (float)(k - 127) * 0.69314718055994530942f;
    a *= scale; b *= scale; c *= scale; d *= scale;
}

template <int S>
__global__ __launch_bounds__(64 * ROWS * WPR) void crf_fwd_k1(
    const float* __restrict__ lstm,   // [B,S,5]
    const float* __restrict__ trans,  // [5,5]
    const int* __restrict__ lens,     // [B]
    const int* __restrict__ tags,     // [B,S]
    float* __restrict__ ws,           // [gridDim.x*2] partials
    int B) {
    constexpr int F4R = S * 5 / 4;   // float4s per lstm row (640 at S=512)
    constexpr int T4R = S / 4;       // int4s per tag row (128 at S=512)
    constexpr int NTHR = 64 * ROWS * WPR;  // 256
    __shared__ float4 xs4[ROWS][F4R];
    __shared__ int4 tg4[ROWS][T4R];
    __shared__ float cw[ROWS][WPR][6];  // m00,m01,m10,m11,logZ,lab
    __shared__ float red[2][ROWS];

    const int tid = threadIdx.x;
    const int lane = tid & 63;
    const int w = tid >> 6;          // wave id in block [0,4)
    const int row = w / WPR;         // which row this wave works on
    const int half = w % WPR;        // time-half of the row
    const int b0 = blockIdx.x * ROWS;

    const int lenA = (b0 < B) ? lens[b0] : 0;
    const int lenB = (b0 + 1 < B) ? lens[b0 + 1] : 0;

    // ---- block-wide coalesced staging, bounded by len ----
    {
        const int nf4_0 = (lenA * 5 + 3) >> 2;
        const int nf4_1 = (lenB * 5 + 3) >> 2;
#pragma unroll
        for (int i = 0; i < (ROWS * F4R) / NTHR; ++i) {  // 5 iters at S=512
            int idx = tid + NTHR * i;
            int r = idx / F4R;
            int j = idx - r * F4R;
            int nf4 = r ? nf4_1 : nf4_0;
            if (j < nf4) {
                const float4* src =
                    reinterpret_cast<const float4*>(lstm + (size_t)(b0 + r) * S * 5);
                xs4[r][j] = src[j];
            }
        }
        const int nt4_0 = (lenA + 3) >> 2;
        const int nt4_1 = (lenB + 3) >> 2;
        {
            int idx = tid;  // 256 threads cover ROWS*T4R = 256 at S=512
            if (idx < ROWS * T4R) {
                int r = idx / T4R;
                int j = idx - r * T4R;
                int nt4 = r ? nt4_1 : nt4_0;
                if (j < nt4) {
                    const int4* tsrc =
                        reinterpret_cast<const int4*>(tags + (size_t)(b0 + r) * S);
                    tg4[r][j] = tsrc[j];
                }
            }
        }
    }
    __syncthreads();

    const int b = b0 + row;
    const bool valid = (b < B);
    const int len = row ? lenB : lenA;
    const float* __restrict__ xr = reinterpret_cast<const float*>(xs4[row]);
    const int* __restrict__ tr = reinterpret_cast<const int*>(tg4[row]);

    // transition scalars (uniform, L2-resident)
    const float T00 = trans[0], T01 = trans[1];
    const float T04 = trans[4];
    const float T10 = trans[5], T11 = trans[6];
    const float T14 = trans[9];
    const float T30 = trans[15], T31 = trans[16];
    const float E00 = __expf(T00), E01 = __expf(T01);
    const float E10 = __expf(T10), E11 = __expf(T11);

    // this lane's segment: t in [tA, tB) subset of [1, len)
    const int tA = 1 + (half * 64 + lane) * SGS;
    const int tB = min(tA + SGS, len);

    float m00 = 1.f, m01 = 0.f, m10 = 0.f, m11 = 1.f;
    float logZ = 0.f;
    float lab = 0.f;

    if (tA < len) {
        int prev = tr[tA - 1] & 1;
#pragma unroll
        for (int u = 0; u < SGS; ++u) {
            int t = tA + u;
            if (t < tB) {
                float x0 = xr[t * 5 + 0];
                float x1 = xr[t * 5 + 1];
                int tg = tr[t] & 1;
                float ex0 = __expf(x0), ex1 = __expf(x1);
                // N = [[E00*ex0, E10*ex0], [E01*ex1, E11*ex1]]
                float n00 = E00 * ex0, n01 = E10 * ex0;
                float n10 = E01 * ex1, n11 = E11 * ex1;
                // M <- N * M
                float r00 = fmaf(n00, m00, n01 * m10);
                float r01 = fmaf(n00, m01, n01 * m11);
                float r10 = fmaf(n10, m00, n11 * m10);
                float r11 = fmaf(n10, m01, n11 * m11);
                m00 = r00; m01 = r01; m10 = r10; m11 = r11;
                // labeled chain: T[prev][tg] + x[t][tg]
                int idx = (prev << 1) | tg;
                float Tpt = (idx == 0) ? T00 : (idx == 1) ? T01
                                         : (idx == 2) ? T10 : T11;
                lab += Tpt + (tg ? x1 : x0);
                if (t == len - 1) lab += tg ? T14 : T04;  // + T[tags[len-1]][END]
                prev = tg;
            }
        }
        rescale4(m00, m01, m10, m11, logZ);  // <= 4 steps: one rescale suffices
    }

    // butterfly within wave: ordered product (higher lane = later = LEFT)
#pragma unroll
    for (int msk = 1; msk < 64; msk <<= 1) {
        float o00 = __shfl_xor(m00, msk);
        float o01 = __shfl_xor(m01, msk);
        float o10 = __shfl_xor(m10, msk);
        float o11 = __shfl_xor(m11, msk);
        float oz = __shfl_xor(logZ, msk);
        float ol = __shfl_xor(lab, msk);
        const bool upper = (lane & msk) != 0;
        float a00 = upper ? m00 : o00, a01 = upper ? m01 : o01;
        float a10 = upper ? m10 : o10, a11 = upper ? m11 : o11;
        float c00 = upper ? o00 : m00, c01 = upper ? o01 : m01;
        float c10 = upper ? o10 : m10, c11 = upper ? o11 : m11;
        m00 = fmaf(a00, c00, a01 * c10);
        m01 = fmaf(a00, c01, a01 * c11);
        m10 = fmaf(a10, c00, a11 * c10);
        m11 = fmaf(a10, c01, a11 * c11);
        logZ += oz;
        lab += ol;
        rescale4(m00, m01, m10, m11, logZ);
    }

    // cross-wave combine per row via LDS
    if (lane == 0) {
        cw[row][half][0] = m00; cw[row][half][1] = m01;
        cw[row][half][2] = m10; cw[row][half][3] = m11;
        cw[row][half][4] = logZ; cw[row][half][5] = lab;
    }
    __syncthreads();

    if (half == 0 && lane == 0) {
        float unlab_w = 0.f, lab_w = 0.f;
        if (valid) {
            // A = earlier half, B = later half; total = MB * MA
            float a00 = cw[row][0][0], a01 = cw[row][0][1];
            float a10 = cw[row][0][2], a11 = cw[row][0][3];
            float b00 = cw[row][1][0], b01 = cw[row][1][1];
            float b10 = cw[row][1][2], b11 = cw[row][1][3];
            float M00 = fmaf(b00, a00, b01 * a10);
            float M01 = fmaf(b00, a01, b01 * a11);
            float M10 = fmaf(b10, a00, b11 * a10);
            float M11 = fmaf(b10, a01, b11 * a11);
            float lz = cw[row][0][4] + cw[row][1][4];
            float lb = cw[row][0][5] + cw[row][1][5];

            float x00 = xr[0], x01 = xr[1];
            int tg0 = tr[0] & 1;
            float p0 = __expf(T30 + x00);   // P0 = exp(T[START][j] + x0[j])
            float p1 = __expf(T31 + x01);
            float f0 = fmaf(M00, p0, M01 * p1);
            float f1 = fmaf(M10, p0, M11 * p1);
            float s = fmaf(f0, __expf(T04), f1 * __expf(T14));
            unlab_w = lz + __logf(s);
            lab_w = lb + (tg0 ? T31 + x01 : T30 + x00);  // begin term
            if (len == 1) lab_w += tg0 ? T14 : T04;      // end term if loop never ran
        }
        red[0][row] = unlab_w;
        red[1][row] = lab_w;
    }
    __syncthreads();
    if (tid == 0) {
        float su = 0.f, sl = 0.f;
#pragma unroll
        for (int r = 0; r < ROWS; ++r) {
            su += red[0][r];
            sl += red[1][r];
        }
        ws[blockIdx.x * 2 + 0] = su;
        ws[blockIdx.x * 2 + 1] = sl;
    }
}

// deterministic final reduce: nblk partial pairs -> out[0..1]
__global__ __launch_bounds__(1024) void crf_reduce(const float* __restrict__ ws,
                                                   float* __restrict__ out,
                                                   int nblk) {
    float su = 0.f, sl = 0.f;
    for (int i = threadIdx.x; i < nblk; i += 1024) {
        float2 v = reinterpret_cast<const float2*>(ws)[i];
        su += v.x;
        sl += v.y;
    }
#pragma unroll
    for (int m = 1; m < 64; m <<= 1) {
        su += __shfl_xor(su, m);
        sl += __shfl_xor(sl, m);
    }
    __shared__ float r[2][16];
    int w = threadIdx.x >> 6, lane = threadIdx.x & 63;
    if (lane == 0) {
        r[0][w] = su;
        r[1][w] = sl;
    }
    __syncthreads();
    if (threadIdx.x == 0) {
        float a = 0.f, b = 0.f;
#pragma unroll
        for (int i = 0; i < 16; ++i) {
            a += r[0][i];
            b += r[1][i];
        }
        out[0] = a;
        out[1] = b;
    }
}

// ---- generic fallback (any S): unstaged wave-parallel, atomics ----
__global__ __launch_bounds__(256) void crf_fwd_wave_gen(
    const float* __restrict__ lstm, const float* __restrict__ trans,
    const int* __restrict__ lens, const int* __restrict__ tags,
    float* __restrict__ out, int B, int S, int Sg) {
    const int lane = threadIdx.x & 63;
    const int wid = threadIdx.x >> 6;
    const int nw = blockDim.x >> 6;
    const int b = blockIdx.x * nw + wid;
    const bool valid = (b < B);

    const float T00 = trans[0], T01 = trans[1];
    const float T04 = trans[4];
    const float T10 = trans[5], T11 = trans[6];
    const float T14 = trans[9];
    const float T30 = trans[15], T31 = trans[16];
    const float E00 = __expf(T00), E01 = __expf(T01);
    const float E10 = __expf(T10), E11 = __expf(T11);

    const int len = valid ? lens[b] : 0;
    const float* __restrict__ xrow = lstm + (size_t)b * S * 5;
    const int* __restrict__ trow = tags + (size_t)b * S;

    const int tA = 1 + lane * Sg;
    const int tB = min(tA + Sg, len);

    float m00 = 1.f, m01 = 0.f, m10 = 0.f, m11 = 1.f;
    float logZ = 0.f, lab = 0.f;

    if (tA < len) {
        int prev = trow[tA - 1] & 1;
        for (int u = 0; u < Sg; ++u) {
            int t = tA + u;
            if (t < tB) {
                float x0 = xrow[t * 5 + 0];
                float x1 = xrow[t * 5 + 1];
                int tg = trow[t] & 1;
                float ex0 = __expf(x0), ex1 = __expf(x1);
                float n00 = E00 * ex0, n01 = E10 * ex0;
                float n10 = E01 * ex1, n11 = E11 * ex1;
                float r00 = fmaf(n00, m00, n01 * m10);
                float r01 = fmaf(n00, m01, n01 * m11);
                float r10 = fmaf(n10, m00, n11 * m10);
                float r11 = fmaf(n10, m01, n11 * m11);
                m00 = r00; m01 = r01; m10 = r10; m11 = r11;
                int idx = (prev << 1) | tg;
                float Tpt = (idx == 0) ? T00 : (idx == 1) ? T01
                                         : (idx == 2) ? T10 : T11;
                lab += Tpt + (tg ? x1 : x0);
                if (t == len - 1) lab += tg ? T14 : T04;
                prev = tg;
            }
            if ((u & 3) == 3) rescale4(m00, m01, m10, m11, logZ);
        }
        rescale4(m00, m01, m10, m11, logZ);
    }

#pragma unroll
    for (int msk = 1; msk < 64; msk <<= 1) {
        float o00 = __shfl_xor(m00, msk);
        float o01 = __shfl_xor(m01, msk);
        float o10 = __shfl_xor(m10, msk);
        float o11 = __shfl_xor(m11, msk);
        float oz = __shfl_xor(logZ, msk);
        float ol = __shfl_xor(lab, msk);
        const bool upper = (lane & msk) != 0;
        float a00 = upper ? m00 : o00, a01 = upper ? m01 : o01;
        float a10 = upper ? m10 : o10, a11 = upper ? m11 : o11;
        float c00 = upper ? o00 : m00, c01 = upper ? o01 : m01;
        float c10 = upper ? o10 : m10, c11 = upper ? o11 : m11;
        m00 = fmaf(a00, c00, a01 * c10);
        m01 = fmaf(a00, c01, a01 * c11);
        m10 = fmaf(a10, c00, a11 * c10);
        m11 = fmaf(a10, c01, a11 * c11);
        logZ += oz;
        lab += ol;
        rescale4(m00, m01, m10, m11, logZ);
    }

    __shared__ float red[2][8];
    float unlab_w = 0.f, lab_w = 0.f;
    if (lane == 0 && valid) {
        float x00 = xrow[0], x01 = xrow[1];
        int tg0 = trow[0] & 1;
        float p0 = __expf(T30 + x00);
        float p1 = __expf(T31 + x01);
        float f0 = fmaf(m00, p0, m01 * p1);
        float f1 = fmaf(m10, p0, m11 * p1);
        float s = fmaf(f0, __expf(T04), f1 * __expf(T14));
        unlab_w = logZ + __logf(s);
        lab_w = lab + (tg0 ? T31 + x01 : T30 + x00);
        if (len == 1) lab_w += tg0 ? T14 : T04;
    }
    if (lane == 0) {
        red[0][wid] = unlab_w;
        red[1][wid] = lab_w;
    }
    __syncthreads();
    if (threadIdx.x == 0) {
        float su = 0.f, sl = 0.f;
        for (int w = 0; w < nw; ++w) {
            su += red[0][w];
            sl += red[1][w];
        }
        atomicAdd(&out[0], su);
        atomicAdd(&out[1], sl);
    }
}

extern "C" void kernel_launch(void* const* d_in, const int* in_sizes, int n_in,
                              void* d_out, int out_size, void* d_ws, size_t ws_size,
                              hipStream_t stream) {
    const float* lstm = (const float*)d_in[0];
    const float* trans = (const float*)d_in[1];
    const int* lens = (const int*)d_in[2];
    const int* tags = (const int*)d_in[3];
    float* out = (float*)d_out;
    float* ws = (float*)d_ws;

    const int B = in_sizes[2];
    const int S = in_sizes[3] / B;

    if (S == 512) {
        const int nblk = (B + ROWS - 1) / ROWS;  // 2048 at B=4096
        dim3 block(64 * ROWS * WPR);             // 256 threads
        crf_fwd_k1<512><<<nblk, block, 0, stream>>>(lstm, trans, lens, tags, ws, B);
        crf_reduce<<<1, 1024, 0, stream>>>(ws, out, nblk);
    } else {
        const int Sg = (S - 1 + 63) >> 6;
        hipMemsetAsync(out, 0, out_size * sizeof(float), stream);
        dim3 block(256);
        dim3 grid((B + 3) / 4);
        crf_fwd_wave_gen<<<grid, block, 0, stream>>>(lstm, trans, lens, tags,
                                                     out, B, S, Sg);
    }
}